// Round 1
// baseline (214.722 us; speedup 1.0000x reference)
//
#include <hip/hip_runtime.h>
#include <math.h>

#define C_CH 256
#define G 14

// ---------------------------------------------------------------------------
// Transpose one FPN level from (C, H, W) to (H*W, C) layout in workspace.
// Classic LDS-tiled transpose of a (C=256) x (S=H*W) matrix.
// Read coalesced along spatial, write coalesced along channel.
// ---------------------------------------------------------------------------
__global__ __launch_bounds__(256) void transpose_chw_hwc(
    const float* __restrict__ src, float* __restrict__ dst, int S) {
  __shared__ float tile[64][65];  // +1 pad: conflict-free transposed reads
  const int tx = threadIdx.x & 63;
  const int ty = threadIdx.x >> 6;  // 0..3
  const int s0 = blockIdx.x * 64;
  const int c0 = blockIdx.y * 64;
  #pragma unroll
  for (int j = 0; j < 16; ++j) {
    int k = ty + 4 * j;
    tile[k][tx] = src[(size_t)(c0 + k) * S + (s0 + tx)];
  }
  __syncthreads();
  #pragma unroll
  for (int j = 0; j < 16; ++j) {
    int k = ty + 4 * j;
    dst[(size_t)(s0 + k) * C_CH + (c0 + tx)] = tile[tx][k];
  }
}

// ---------------------------------------------------------------------------
// ROI Align + 2x2 max pool. One 64-thread block per (proposal, 64-ch chunk).
// TR=true : read transposed (H,W,C) features from tf  (coalesced, fast path)
// TR=false: read (C,H,W) features directly            (fallback, no ws)
// ---------------------------------------------------------------------------
template <bool TR>
__global__ __launch_bounds__(64) void roi_kernel(
    const float* __restrict__ f0, const float* __restrict__ f1,
    const float* __restrict__ f2, const float* __restrict__ f3,
    const float* __restrict__ tf, const float* __restrict__ proposals,
    float* __restrict__ out) {
  __shared__ int xo0[G], xo1[G], yo0[G], yo1[G];
  __shared__ float wxa[G], wxb[G], wya[G], wyb[G];
  __shared__ float obuf[64 * 49];

  const int n = blockIdx.x;
  const int cblk = blockIdx.y;
  const int lane = threadIdx.x;
  const int c = cblk * 64 + lane;

  const float px1 = proposals[n * 4 + 0];
  const float py1 = proposals[n * 4 + 1];
  const float px2 = proposals[n * 4 + 2];
  const float py2 = proposals[n * 4 + 3];
  const float pw = px2 - px1;
  const float ph = py2 - py1;
  // lvl = clip(floor(2 + log2(sqrt(pw*ph)/224)), 0, 3)
  float t = 2.0f + log2f(sqrtf(pw * ph) / 224.0f);
  int lvl = (int)floorf(t);
  lvl = lvl < 0 ? 0 : (lvl > 3 ? 3 : lvl);

  const float scales[4] = {0.25f, 0.125f, 0.0625f, 0.03125f};
  const int sizes[4] = {256, 128, 64, 32};
  const int offs[4] = {0, 65536, 81920, 86016};  // spatial prefix offsets
  const float sc = scales[lvl];
  const int sz = sizes[lvl];

  const float bx1 = px1 * sc, by1 = py1 * sc;
  const float bx2 = px2 * sc, by2 = py2 * sc;
  const float w_unit = ((bx2 - bx1) / 7.0f) * 0.5f;
  const float h_unit = ((by2 - by1) / 7.0f) * 0.5f;

  // Per-wave sample tables (uniform across channels).
  if (lane < G) {
    const int i = lane;
    float x = bx1 + ((float)i + 0.5f) * w_unit;
    int xf = (int)floorf(x);
    int x0 = min(max(xf, 0), sz - 1);
    int x1 = min(max(xf + 1, 0), sz - 1);
    wxa[i] = (float)x1 - x;  // matches ref's (x1f - x) incl. clipped extrap.
    wxb[i] = x - (float)x0;
    xo0[i] = TR ? x0 * C_CH : x0;
    xo1[i] = TR ? x1 * C_CH : x1;
  } else if (lane >= 32 && lane < 32 + G) {
    const int i = lane - 32;
    float y = by1 + ((float)i + 0.5f) * h_unit;
    int yf = (int)floorf(y);
    int y0 = min(max(yf, 0), sz - 1);
    int y1 = min(max(yf + 1, 0), sz - 1);
    wya[i] = (float)y1 - y;
    wyb[i] = y - (float)y0;
    yo0[i] = TR ? y0 * sz * C_CH : y0 * sz;
    yo1[i] = TR ? y1 * sz * C_CH : y1 * sz;
  }
  __syncthreads();

  const float* base;
  if (TR) {
    base = tf + (size_t)offs[lvl] * C_CH + c;
  } else {
    const float* fl = (lvl == 0) ? f0 : (lvl == 1) ? f1 : (lvl == 2) ? f2 : f3;
    base = fl + (size_t)c * sz * sz;
  }

  for (int oh = 0; oh < 7; ++oh) {
    float mm[7];
    #pragma unroll
    for (int ow = 0; ow < 7; ++ow) mm[ow] = -INFINITY;
    #pragma unroll
    for (int sy = 0; sy < 2; ++sy) {
      const int gy = oh * 2 + sy;
      const float* r0 = base + yo0[gy];
      const float* r1 = base + yo1[gy];
      const float wy0 = wya[gy];
      const float wy1 = wyb[gy];
      #pragma unroll
      for (int gx = 0; gx < G; ++gx) {
        float f00 = r0[xo0[gx]];
        float f01 = r0[xo1[gx]];
        float f10 = r1[xo0[gx]];
        float f11 = r1[xo1[gx]];
        float v = wy0 * (wxa[gx] * f00 + wxb[gx] * f01) +
                  wy1 * (wxa[gx] * f10 + wxb[gx] * f11);
        mm[gx >> 1] = fmaxf(mm[gx >> 1], v);
      }
    }
    #pragma unroll
    for (int ow = 0; ow < 7; ++ow) obuf[lane * 49 + oh * 7 + ow] = mm[ow];
  }
  __syncthreads();

  // Coalesced block store: this block owns a contiguous 64*49-float region.
  float* ob = out + ((size_t)n * C_CH + (size_t)cblk * 64) * 49;
  for (int idx = lane; idx < 64 * 49; idx += 64) ob[idx] = obuf[idx];
}

extern "C" void kernel_launch(void* const* d_in, const int* in_sizes, int n_in,
                              void* d_out, int out_size, void* d_ws,
                              size_t ws_size, hipStream_t stream) {
  const float* f0 = (const float*)d_in[0];
  const float* f1 = (const float*)d_in[1];
  const float* f2 = (const float*)d_in[2];
  const float* f3 = (const float*)d_in[3];
  const float* props = (const float*)d_in[4];
  float* out = (float*)d_out;
  const int N = in_sizes[4] / 4;

  const size_t needed = (size_t)87040 * C_CH * sizeof(float);  // ~89.1 MB
  if (ws_size >= needed) {
    float* tf = (float*)d_ws;
    const float* srcs[4] = {f0, f1, f2, f3};
    const int S[4] = {65536, 16384, 4096, 1024};
    const size_t off[4] = {0, 65536, 81920, 86016};
    for (int l = 0; l < 4; ++l) {
      dim3 g(S[l] / 64, 4);
      transpose_chw_hwc<<<g, 256, 0, stream>>>(srcs[l], tf + off[l] * C_CH,
                                               S[l]);
    }
    roi_kernel<true><<<dim3(N, 4), 64, 0, stream>>>(f0, f1, f2, f3, tf, props,
                                                    out);
  } else {
    roi_kernel<false><<<dim3(N, 4), 64, 0, stream>>>(f0, f1, f2, f3, nullptr,
                                                     props, out);
  }
}